// Round 3
// baseline (9346.709 us; speedup 1.0000x reference)
//
#include <hip/hip_runtime.h>
#include <hip/hip_bf16.h>
#include <math.h>

#define N_TOK   32768
#define DIM     256
#define KC      8192
#define BM      64
#define BN      64
#define BD      32
#define NCHUNK  (DIM / BD)        // 8
#define NKT     (KC / BN)         // 128
#define TOTCH   (NKT * NCHUNK)    // 1024

// output layout (flat f32, reference tuple order)
#define OUT_ZQ    0
#define OUT_IDX   8388608          // N_TOK*DIM
#define OUT_LOSS  8421376          // +N_TOK
#define OUT_NEMB  8421377          // +1
#define OUT_CS    10518529         // +KC*DIM
#define OUT_SUM   10526721         // +KC

// LDS swizzle: keeps float4 contiguity (XOR by multiple of 4), spreads the
// transposing ds_writes across 8 banks (2-way conflict = free, m136).
__device__ __forceinline__ int swz(int d, int x) {
  return (d << 6) | (x ^ (((d >> 2) & 7) << 2));
}

__global__ void vq_esq(const float* __restrict__ emb, float* __restrict__ esq) {
  const int g = blockIdx.x * blockDim.x + threadIdx.x;
  const int code = g >> 6;
  const int lane = g & 63;
  const float4 v = *(const float4*)(emb + (size_t)code * DIM + (lane << 2));
  float s = fmaf(v.x, v.x, fmaf(v.y, v.y, fmaf(v.z, v.z, v.w * v.w)));
  #pragma unroll
  for (int off = 32; off; off >>= 1) s += __shfl_down(s, off);
  if (lane == 0) esq[code] = s;
}

__global__ void vq_init(const float* __restrict__ ema_sum,
                        const float* __restrict__ ema_cs,
                        float* __restrict__ out, float* __restrict__ lossws) {
  const int i = blockIdx.x * blockDim.x + threadIdx.x;
  out[OUT_SUM + i] = 0.99f * ema_sum[i];
  if (i < KC) out[OUT_CS + i] = 0.99f * ema_cs[i];
  if (i == 0) lossws[0] = 0.f;
}

// lexicographic (val, idx) min helper
__device__ __forceinline__ bool lexlt(float av, int ai, float bv, int bi) {
  return (av < bv) || (av == bv && ai < bi);
}

__launch_bounds__(256, 2)
__global__ void vq_argmin(const float* __restrict__ z,
                          const float* __restrict__ emb,
                          const float* __restrict__ esq,
                          int2* __restrict__ cand) {
  extern __shared__ float smem[];
  float* Zs  = smem;              // 256 x 64 (swizzled) = 16384 f32
  float* Es0 = smem + 16384;      // 2 x (32 x 64) = 4096 f32

  const int tid = threadIdx.x;
  const int tx  = tid & 15;
  const int ty  = tid >> 4;
  const int tx4 = tx << 2;
  const int ty4 = ty << 2;
  const int row0 = blockIdx.x * BM;

  // stage Z tile (64 rows x 256 d), transposed into swizzled LDS
  #pragma unroll
  for (int i = 0; i < 16; ++i) {
    int f = tid + (i << 8);
    int r = f >> 6;
    int d0 = (f & 63) << 2;
    float4 v = *(const float4*)(z + (size_t)(row0 + r) * DIM + d0);
    Zs[swz(d0 + 0, r)] = v.x;
    Zs[swz(d0 + 1, r)] = v.y;
    Zs[swz(d0 + 2, r)] = v.z;
    Zs[swz(d0 + 3, r)] = v.w;
  }

  float4 pre0, pre1;
  // prologue: stage E chunk 0 (ktile 0, dchunk 0) into buffer 0
  {
    int f0 = tid, f1 = tid + 256;
    int jj0 = f0 >> 3, dd0 = (f0 & 7) << 2;
    int jj1 = f1 >> 3, dd1 = (f1 & 7) << 2;
    pre0 = *(const float4*)(emb + (size_t)jj0 * DIM + dd0);
    pre1 = *(const float4*)(emb + (size_t)jj1 * DIM + dd1);
    Es0[swz(dd0 + 0, jj0)] = pre0.x; Es0[swz(dd0 + 1, jj0)] = pre0.y;
    Es0[swz(dd0 + 2, jj0)] = pre0.z; Es0[swz(dd0 + 3, jj0)] = pre0.w;
    Es0[swz(dd1 + 0, jj1)] = pre1.x; Es0[swz(dd1 + 1, jj1)] = pre1.y;
    Es0[swz(dd1 + 2, jj1)] = pre1.z; Es0[swz(dd1 + 3, jj1)] = pre1.w;
  }

  float b1v[4] = {3.4e38f, 3.4e38f, 3.4e38f, 3.4e38f};
  float b2v[4] = {3.4e38f, 3.4e38f, 3.4e38f, 3.4e38f};
  int   b1i[4] = {0x7fffffff, 0x7fffffff, 0x7fffffff, 0x7fffffff};
  int   b2i[4] = {0x7fffffff, 0x7fffffff, 0x7fffffff, 0x7fffffff};

  for (int kt = 0; kt < NKT; ++kt) {
    float acc[4][4];
    #pragma unroll
    for (int i = 0; i < 4; ++i)
      #pragma unroll
      for (int j = 0; j < 4; ++j) acc[i][j] = 0.f;

    #pragma unroll 1
    for (int c = 0; c < NCHUNK; ++c) {
      const int p = kt * NCHUNK + c;
      __syncthreads();               // chunk p staged; prev compute done
      const int np = p + 1;
      const bool hn = (np < TOTCH);
      int jj0 = 0, dd0 = 0, jj1 = 0, dd1 = 0;
      if (hn) {                      // T14: issue loads early (hide under FMA)
        const float* src = emb + (size_t)(np >> 3) * (BN * DIM) + (np & 7) * BD;
        int f0 = tid, f1 = tid + 256;
        jj0 = f0 >> 3; dd0 = (f0 & 7) << 2;
        jj1 = f1 >> 3; dd1 = (f1 & 7) << 2;
        pre0 = *(const float4*)(src + (size_t)jj0 * DIM + dd0);
        pre1 = *(const float4*)(src + (size_t)jj1 * DIM + dd1);
      }
      const float* E = Es0 + (p & 1) * (BD * 64);
      #pragma unroll
      for (int dd = 0; dd < BD; ++dd) {
        const int dg = c * BD + dd;
        const float4 a = *(const float4*)(Zs + swz(dg, ty4));
        const float4 b = *(const float4*)(E + swz(dd, tx4));
        const float av[4] = {a.x, a.y, a.z, a.w};
        const float bv[4] = {b.x, b.y, b.z, b.w};
        #pragma unroll
        for (int i = 0; i < 4; ++i)
          #pragma unroll
          for (int j = 0; j < 4; ++j)
            acc[i][j] = fmaf(av[i], bv[j], acc[i][j]);
      }
      if (hn) {                      // write-late into the other buffer
        float* En = Es0 + (np & 1) * (BD * 64);
        En[swz(dd0 + 0, jj0)] = pre0.x; En[swz(dd0 + 1, jj0)] = pre0.y;
        En[swz(dd0 + 2, jj0)] = pre0.z; En[swz(dd0 + 3, jj0)] = pre0.w;
        En[swz(dd1 + 0, jj1)] = pre1.x; En[swz(dd1 + 1, jj1)] = pre1.y;
        En[swz(dd1 + 2, jj1)] = pre1.z; En[swz(dd1 + 3, jj1)] = pre1.w;
      }
    }

    // epilogue: score = e_sq - 2*z.e (argmin-equivalent); track top-2
    const float4 eq = *(const float4*)(esq + kt * BN + tx4);
    const float eqv[4] = {eq.x, eq.y, eq.z, eq.w};
    #pragma unroll
    for (int i = 0; i < 4; ++i) {
      #pragma unroll
      for (int j = 0; j < 4; ++j) {
        const int code = kt * BN + tx4 + j;
        const float s = fmaf(-2.f, acc[i][j], eqv[j]);
        if (lexlt(s, code, b1v[i], b1i[i])) {
          b2v[i] = b1v[i]; b2i[i] = b1i[i];
          b1v[i] = s;      b1i[i] = code;
        } else if (lexlt(s, code, b2v[i], b2i[i])) {
          b2v[i] = s; b2i[i] = code;
        }
      }
    }
  }

  // merge sorted top-2 pairs across the 16 tx lanes of each row group
  #pragma unroll
  for (int i = 0; i < 4; ++i) {
    float a1v = b1v[i], a2v = b2v[i];
    int   a1i = b1i[i], a2i = b2i[i];
    #pragma unroll
    for (int off = 1; off < 16; off <<= 1) {
      float o1v = __shfl_xor(a1v, off); int o1i = __shfl_xor(a1i, off);
      float o2v = __shfl_xor(a2v, off); int o2i = __shfl_xor(a2i, off);
      if (lexlt(o1v, o1i, a1v, a1i)) {
        float n2v; int n2i;
        if (lexlt(a1v, a1i, o2v, o2i)) { n2v = a1v; n2i = a1i; }
        else                           { n2v = o2v; n2i = o2i; }
        a1v = o1v; a1i = o1i; a2v = n2v; a2i = n2i;
      } else {
        if (lexlt(o1v, o1i, a2v, a2i)) { a2v = o1v; a2i = o1i; }
      }
    }
    if (tx == 0) cand[row0 + ty4 + i] = make_int2(a1i, a2i);
  }
}

// ---- numpy-f32 emulation rescore ----
// numpy pairwise sum of squares for n=256: two 128-blocks, each with 8
// sequential accumulators (16 terms each), combined ((r0+r1)+(r2+r3))+((r4+r5)+(r6+r7)),
// then left_half + right_half. All ops __fmul_rn/__fadd_rn (no FMA contraction).
// 16 lanes per sum: lane = h*8+j; h = half, j = accumulator.
// Valid result at group-base lane after the shfl tree.
__device__ __forceinline__ float np_sumsq256(const float* __restrict__ p, int lane) {
  const int l = lane & 15;
  const int h = l >> 3;
  const int j = l & 7;
  const float* a = p + h * 128 + j;
  float x = a[0];
  float r = __fmul_rn(x, x);
  #pragma unroll
  for (int i = 1; i < 16; ++i) {
    x = a[8 * i];
    r = __fadd_rn(r, __fmul_rn(x, x));
  }
  // combine accumulators: ((r0+r1)+(r2+r3)) + ((r4+r5)+(r6+r7))
  r = __fadd_rn(r, __shfl_down(r, 1));   // valid at even j
  r = __fadd_rn(r, __shfl_down(r, 2));   // valid at j=0,4
  r = __fadd_rn(r, __shfl_down(r, 4));   // valid at j=0
  // halves: left + right  (half bases are group_base and group_base+8)
  float hi = __shfl(r, (lane & 48) | 8);
  return __fadd_rn(r, hi);               // valid at lanes 0,16,32,48
}

// one wave per row; emulates numpy f32: D = fl(fl(zsq+esq) - fl(2*ze)),
// ze = sequential f32 FMA chain over k (OpenBLAS sgemm microkernel order),
// argmin tie -> lowest index (numpy first-occurrence).
__global__ void vq_rescore(const float* __restrict__ z,
                           const float* __restrict__ emb,
                           const int2* __restrict__ cand,
                           int* __restrict__ idxf) {
  const int tid  = threadIdx.x;
  const int lane = tid & 63;
  const int w    = tid >> 6;
  const int row  = blockIdx.x * 4 + w;
  const int2 c   = cand[row];
  const float* zr = z + (size_t)row * DIM;
  const float* ea = emb + (size_t)c.x * DIM;
  const float* eb = emb + (size_t)c.y * DIM;

  // three pairwise sums in parallel: lanes 0-15 zsq, 16-31 esq_a, 32-47 esq_b
  const int task = lane >> 4;
  const float* p = (task == 0) ? zr : (task == 1) ? ea : eb;
  const float sums = np_sumsq256(p, lane);
  const float zsq  = __shfl(sums, 0);
  const float esqa = __shfl(sums, 16);
  const float esqb = __shfl(sums, 32);

  // sequential FMA chains: lane 0 -> candidate a, lane 1 -> candidate b
  const float* er = (lane == 0) ? ea : eb;
  float ze = 0.f;
  #pragma unroll 8
  for (int k = 0; k < DIM; ++k) ze = fmaf(zr[k], er[k], ze);
  const float zea = __shfl(ze, 0);
  const float zeb = __shfl(ze, 1);

  if (lane == 0) {
    const float Da = __fsub_rn(__fadd_rn(zsq, esqa), __fmul_rn(2.f, zea));
    const float Db = __fsub_rn(__fadd_rn(zsq, esqb), __fmul_rn(2.f, zeb));
    int win;
    if (Da < Db)      win = c.x;
    else if (Db < Da) win = c.y;
    else              win = (c.x < c.y) ? c.x : c.y;
    idxf[row] = win;
  }
}

__global__ void vq_scatter(const float* __restrict__ z,
                           const float* __restrict__ emb,
                           const int* __restrict__ idx,
                           float* __restrict__ out,
                           float* __restrict__ lossws) {
  __shared__ float part[4];
  const int row = blockIdx.x;
  const int t = threadIdx.x;
  const int code = idx[row];
  const float zv = z[(size_t)row * DIM + t];
  const float ev = emb[(size_t)code * DIM + t];
  const float d = ev - zv;
  out[OUT_ZQ + (size_t)row * DIM + t] = zv + d;   // straight-through = z + (zq - z)
  atomicAdd(out + OUT_SUM + (size_t)code * DIM + t, 0.01f * zv);
  float sq = d * d;
  #pragma unroll
  for (int off = 32; off; off >>= 1) sq += __shfl_down(sq, off);
  const int lane = t & 63, w = t >> 6;
  if (lane == 0) part[w] = sq;
  __syncthreads();
  if (t == 0) {
    atomicAdd(lossws, part[0] + part[1] + part[2] + part[3]);
    atomicAdd(out + OUT_CS + code, 0.01f);
    out[OUT_IDX + row] = (float)code;
  }
}

__global__ void vq_finalize(float* __restrict__ out, const float* __restrict__ lossws) {
  const int i = blockIdx.x * blockDim.x + threadIdx.x;
  const int k = i >> 8;
  const float cs = out[OUT_CS + k];
  out[OUT_NEMB + i] = out[OUT_SUM + i] / (cs + 1e-5f);
  if (i == 0) out[OUT_LOSS] = 0.25f * (lossws[0] * (1.f / 8388608.f)); // /2^23, *0.25 exact
}

extern "C" void kernel_launch(void* const* d_in, const int* in_sizes, int n_in,
                              void* d_out, int out_size, void* d_ws, size_t ws_size,
                              hipStream_t stream) {
  const float* z      = (const float*)d_in[0];
  const float* emb    = (const float*)d_in[1];
  const float* emacs  = (const float*)d_in[2];
  const float* emasum = (const float*)d_in[3];
  float* out = (float*)d_out;
  float* ws  = (float*)d_ws;

  float* esq    = ws;                              // 8192 f32
  int2*  cand   = (int2*)(ws + KC);                // 32768 int2
  int*   idxf   = (int*)(ws + KC + 2 * N_TOK);     // 32768 i32
  float* lossws = ws + KC + 3 * N_TOK;             // 1 f32

  vq_esq<<<KC / 4, 256, 0, stream>>>(emb, esq);
  vq_init<<<(KC * DIM) / 256, 256, 0, stream>>>(emasum, emacs, out, lossws);

  (void)hipFuncSetAttribute(reinterpret_cast<const void*>(vq_argmin),
                            hipFuncAttributeMaxDynamicSharedMemorySize, 81920);
  vq_argmin<<<N_TOK / BM, 256, 81920, stream>>>(z, emb, esq, cand);

  vq_rescore<<<N_TOK / 4, 256, 0, stream>>>(z, emb, cand, idxf);
  vq_scatter<<<N_TOK, 256, 0, stream>>>(z, emb, idxf, out, lossws);
  vq_finalize<<<(KC * DIM) / 256, 256, 0, stream>>>(out, lossws);
}

// Round 4
// 1164.633 us; speedup vs baseline: 8.0255x; 8.0255x over previous
//
#include <hip/hip_runtime.h>
#include <hip/hip_bf16.h>
#include <math.h>

#define N_TOK   32768
#define DIM     256
#define KC      8192

// output layout (flat f32, reference tuple order)
#define OUT_ZQ    0
#define OUT_IDX   8388608          // N_TOK*DIM
#define OUT_LOSS  8421376          // +N_TOK
#define OUT_NEMB  8421377          // +1
#define OUT_CS    10518529         // +KC*DIM
#define OUT_SUM   10526721         // +KC

#define MARGIN  2.5e-4f
#define FLAGCAP 4096

typedef __attribute__((ext_vector_type(8))) __bf16 bf16x8;
typedef __attribute__((ext_vector_type(4))) float f32x4;

__device__ __forceinline__ void gload16(const void* g, void* l) {
  __builtin_amdgcn_global_load_lds((const __attribute__((address_space(1))) void*)g,
                                   (__attribute__((address_space(3))) void*)l, 16, 0, 0);
}

// ---- numpy pairwise sum-of-squares emulation (validated in R3) ----
// n=256: two 128-halves, 8 sequential accumulators of 16 terms, combined
// ((r0+r1)+(r2+r3))+((r4+r5)+(r6+r7)), halves added last. 16 lanes per sum;
// valid at each 16-lane group's base lane.
__device__ __forceinline__ float np_sumsq256(const float* __restrict__ p, int lane) {
  const int l = lane & 15;
  const int h = l >> 3;
  const int j = l & 7;
  const float* a = p + h * 128 + j;
  float x = a[0];
  float r = __fmul_rn(x, x);
  #pragma unroll
  for (int i = 1; i < 16; ++i) {
    x = a[8 * i];
    r = __fadd_rn(r, __fmul_rn(x, x));
  }
  r = __fadd_rn(r, __shfl_down(r, 1));
  r = __fadd_rn(r, __shfl_down(r, 2));
  r = __fadd_rn(r, __shfl_down(r, 4));
  float hi = __shfl(r, (lane & 48) | 8);
  return __fadd_rn(r, hi);
}

// numpy-exact e_sq for all codes (16 lanes per code, 16 codes per block)
__global__ void vq_esq_np(const float* __restrict__ emb, float* __restrict__ esq) {
  const int tid = threadIdx.x;
  const int code = blockIdx.x * 16 + (tid >> 4);
  const float s = np_sumsq256(emb + (size_t)code * DIM, tid & 63);
  if ((tid & 15) == 0) esq[code] = s;
}

// build e_split[8192][768] bf16 = [e_hi | e_hi | e_lo]
__global__ void vq_esplit(const float* __restrict__ emb, short* __restrict__ esp) {
  const int gidx = blockIdx.x * blockDim.x + threadIdx.x;   // [0, 262144)
  const int code = gidx >> 5;
  const int seg  = gidx & 31;
  const float* p = emb + (size_t)code * DIM + seg * 8;
  const float4 v0 = *(const float4*)p;
  const float4 v1 = *(const float4*)(p + 4);
  const float xf[8] = {v0.x, v0.y, v0.z, v0.w, v1.x, v1.y, v1.z, v1.w};
  bf16x8 hi, lo;
  #pragma unroll
  for (int e = 0; e < 8; ++e) {
    __bf16 hb = (__bf16)xf[e];
    hi[e] = hb;
    lo[e] = (__bf16)(xf[e] - (float)hb);
  }
  short* rp = esp + (size_t)code * 768 + seg * 8;
  *(bf16x8*)(rp)       = hi;
  *(bf16x8*)(rp + 256) = hi;
  *(bf16x8*)(rp + 512) = lo;
}

__global__ void vq_init(const float* __restrict__ ema_sum,
                        const float* __restrict__ ema_cs,
                        float* __restrict__ out,
                        float* __restrict__ lossws,
                        int* __restrict__ cnt) {
  const int i = blockIdx.x * blockDim.x + threadIdx.x;
  out[OUT_SUM + i] = 0.99f * ema_sum[i];
  if (i < KC) out[OUT_CS + i] = 0.99f * ema_cs[i];
  if (i == 0) { lossws[0] = 0.f; cnt[0] = 0; }
}

// ---- MFMA argmin: 256 blocks x 256 thr; wave owns 32 rows, A in registers,
// B (e_split) streamed through 2x32KB LDS with both-sides XOR swizzle ----
__launch_bounds__(256, 2)
__global__ void vq_mfma(const float* __restrict__ z,
                        const short* __restrict__ esp,
                        const float* __restrict__ esq,
                        int* __restrict__ idxf,
                        int* __restrict__ flag,
                        int* __restrict__ cnt) {
  __shared__ char lds[65536];
  const int tid  = threadIdx.x;
  const int lane = tid & 63;
  const int w    = tid >> 6;
  const int l15  = lane & 15;
  const int g    = lane >> 4;
  const int row0 = blockIdx.x * 128 + w * 32;

  // staging constants: linear LDS byte b=((i*4+w)*64+lane)*16 holds source
  // byte (code*1536 + ch*512 + (kb ^ ((code&7)<<4))) of the tile
  const int l5  = lane >> 5;
  const int kb  = (lane & 31) << 4;
  const int cc2 = ((w << 1) + l5) & 7;          // (code&7), constant per lane
  const int kbx = kb ^ (cc2 << 4);
  const int c2b = (w << 1) + l5;                 // code = c2b + i*8
  const char* espb = (const char*)esp;

#define STAGE(CT, CH, BUFB)                                                     \
  {                                                                             \
    const char* sb_ = espb + (size_t)(CT) * 98304 + (CH) * 512 + kbx;           \
    _Pragma("unroll")                                                           \
    for (int i_ = 0; i_ < 8; ++i_) {                                            \
      gload16(sb_ + (size_t)(c2b + i_ * 8) * 1536,                              \
              (void*)(lds + (BUFB) + ((i_ * 4 + w) << 10)));                    \
    }                                                                           \
  }

  STAGE(0, 0, 0);

  // A: load z rows, convert to bf16 hi/lo fragments (hi reused for chunk 2)
  bf16x8 Ahi[2][8], Alo[2][8];
  #pragma unroll
  for (int s = 0; s < 2; ++s) {
    const float* zr = z + (size_t)(row0 + s * 16 + l15) * DIM + g * 8;
    #pragma unroll
    for (int c = 0; c < 8; ++c) {
      const float4 v0 = *(const float4*)(zr + c * 32);
      const float4 v1 = *(const float4*)(zr + c * 32 + 4);
      const float xf[8] = {v0.x, v0.y, v0.z, v0.w, v1.x, v1.y, v1.z, v1.w};
      #pragma unroll
      for (int e = 0; e < 8; ++e) {
        __bf16 hb = (__bf16)xf[e];
        Ahi[s][c][e] = hb;
        Alo[s][c][e] = (__bf16)(xf[e] - (float)hb);
      }
    }
  }

  __syncthreads();   // chunk(0,0) staged

  float b1[2][4], b2[2][4];
  int   i1[2][4];
  #pragma unroll
  for (int s = 0; s < 2; ++s)
    #pragma unroll
    for (int r = 0; r < 4; ++r) { b1[s][r] = 3.4e38f; b2[s][r] = 3.4e38f; i1[s][r] = 0x7fffffff; }

  const int g16 = g << 4;
  const int X   = (l15 & 7) << 4;
  const int ro0 = (l15)      * 512;
  const int ro1 = (16 + l15) * 512;
  const int ro2 = (32 + l15) * 512;
  const int ro3 = (48 + l15) * 512;

#define COMP(BUFB, AARR)                                                              \
  {                                                                                   \
    _Pragma("unroll")                                                                 \
    for (int j_ = 0; j_ < 8; ++j_) {                                                  \
      const int kx_ = ((j_ << 6) + g16) ^ X;                                          \
      const bf16x8 bF0 = *(const bf16x8*)(lds + (BUFB) + ro0 + kx_);                  \
      const bf16x8 bF1 = *(const bf16x8*)(lds + (BUFB) + ro1 + kx_);                  \
      const bf16x8 bF2 = *(const bf16x8*)(lds + (BUFB) + ro2 + kx_);                  \
      const bf16x8 bF3 = *(const bf16x8*)(lds + (BUFB) + ro3 + kx_);                  \
      acc[0][0] = __builtin_amdgcn_mfma_f32_16x16x32_bf16(AARR[0][j_], bF0, acc[0][0], 0, 0, 0); \
      acc[0][1] = __builtin_amdgcn_mfma_f32_16x16x32_bf16(AARR[0][j_], bF1, acc[0][1], 0, 0, 0); \
      acc[0][2] = __builtin_amdgcn_mfma_f32_16x16x32_bf16(AARR[0][j_], bF2, acc[0][2], 0, 0, 0); \
      acc[0][3] = __builtin_amdgcn_mfma_f32_16x16x32_bf16(AARR[0][j_], bF3, acc[0][3], 0, 0, 0); \
      acc[1][0] = __builtin_amdgcn_mfma_f32_16x16x32_bf16(AARR[1][j_], bF0, acc[1][0], 0, 0, 0); \
      acc[1][1] = __builtin_amdgcn_mfma_f32_16x16x32_bf16(AARR[1][j_], bF1, acc[1][1], 0, 0, 0); \
      acc[1][2] = __builtin_amdgcn_mfma_f32_16x16x32_bf16(AARR[1][j_], bF2, acc[1][2], 0, 0, 0); \
      acc[1][3] = __builtin_amdgcn_mfma_f32_16x16x32_bf16(AARR[1][j_], bF3, acc[1][3], 0, 0, 0); \
    }                                                                                 \
  }

  int bp = 0;
  for (int ct = 0; ct < 128; ++ct) {
    float eqv[4];
    #pragma unroll
    for (int sub = 0; sub < 4; ++sub) eqv[sub] = esq[(ct << 6) + sub * 16 + l15];

    f32x4 acc[2][4];
    #pragma unroll
    for (int s = 0; s < 2; ++s)
      #pragma unroll
      for (int sub = 0; sub < 4; ++sub) acc[s][sub] = (f32x4){0.f, 0.f, 0.f, 0.f};

    const int bo  = bp << 15;
    const int bo1 = bo ^ 32768;

    STAGE(ct, 1, bo1);                    // chunk1 (e_hi copy) -> other buf
    COMP(bo, Ahi);                        // chunk0: z_hi . e_hi
    __syncthreads();

    STAGE(ct, 2, bo);                     // chunk2 (e_lo) -> buf0
    COMP(bo1, Alo);                       // chunk1: z_lo . e_hi
    __syncthreads();

    if (ct < 127) STAGE(ct + 1, 0, bo1);  // next tile chunk0
    COMP(bo, Ahi);                        // chunk2: z_hi . e_lo
    __syncthreads();

    // epilogue: score = esq - 2*(z.e); track (min, idx) + 2nd-min value
    #pragma unroll
    for (int s = 0; s < 2; ++s) {
      #pragma unroll
      for (int sub = 0; sub < 4; ++sub) {
        const int codeS = (ct << 6) + sub * 16 + l15;
        #pragma unroll
        for (int r = 0; r < 4; ++r) {
          const float sc = fmaf(-2.f, acc[s][sub][r], eqv[sub]);
          const bool lt = sc < b1[s][r];
          b2[s][r] = fminf(b2[s][r], fmaxf(sc, b1[s][r]));
          i1[s][r] = lt ? codeS : i1[s][r];
          b1[s][r] = fminf(b1[s][r], sc);
        }
      }
    }
    bp ^= 1;
  }

  // merge across the 16 lanes sharing each output row
  #pragma unroll
  for (int s = 0; s < 2; ++s) {
    #pragma unroll
    for (int r = 0; r < 4; ++r) {
      float v1 = b1[s][r], v2 = b2[s][r];
      int   j1 = i1[s][r];
      #pragma unroll
      for (int off = 1; off < 16; off <<= 1) {
        const float o1 = __shfl_xor(v1, off);
        const int   oj = __shfl_xor(j1, off);
        const float o2 = __shfl_xor(v2, off);
        v2 = fminf(fminf(v2, o2), fmaxf(v1, o1));
        const bool tk = (o1 < v1) || (o1 == v1 && oj < j1);
        j1 = tk ? oj : j1;
        v1 = fminf(v1, o1);
      }
      if (l15 == 0) {
        const int row = row0 + s * 16 + (g << 2) + r;
        idxf[row] = j1;
        if (v2 - v1 < MARGIN) {
          const int p = atomicAdd(cnt, 1);
          if (p < FLAGCAP) flag[p] = row;
        }
      }
    }
  }
}

// numpy-exact full rescan for flagged (near-tie) rows
__global__ void vq_rescan(const float* __restrict__ z,
                          const float* __restrict__ emb,
                          const float* __restrict__ esq,
                          const int* __restrict__ flag,
                          const int* __restrict__ cnt,
                          int* __restrict__ idxf) {
  __shared__ float zrow[256];
  __shared__ float zsq_sh;
  __shared__ float rv[4];
  __shared__ int   ri[4];
  int n = *cnt; if (n > FLAGCAP) n = FLAGCAP;
  const int tid = threadIdx.x;
  for (int ii = blockIdx.x; ii < n; ii += gridDim.x) {
    const int row = flag[ii];
    __syncthreads();
    zrow[tid] = z[(size_t)row * DIM + tid];
    __syncthreads();
    if (tid < 16) { const float s = np_sumsq256(zrow, tid); if (tid == 0) zsq_sh = s; }
    __syncthreads();
    const float zsq = zsq_sh;
    float bv = 3.4e38f; int bi = 0x7fffffff;
    for (int cc = 0; cc < 32; ++cc) {
      const int code = cc * 256 + tid;
      const float* e = emb + (size_t)code * DIM;
      float ze = 0.f;
      #pragma unroll 4
      for (int k4 = 0; k4 < 64; ++k4) {
        const float4 ev = *(const float4*)(e + k4 * 4);
        ze = fmaf(zrow[k4 * 4 + 0], ev.x, ze);
        ze = fmaf(zrow[k4 * 4 + 1], ev.y, ze);
        ze = fmaf(zrow[k4 * 4 + 2], ev.z, ze);
        ze = fmaf(zrow[k4 * 4 + 3], ev.w, ze);
      }
      const float D = __fsub_rn(__fadd_rn(zsq, esq[code]), __fmul_rn(2.f, ze));
      if (D < bv) { bv = D; bi = code; }
    }
    const int lane = tid & 63, wv = tid >> 6;
    #pragma unroll
    for (int off = 32; off; off >>= 1) {
      const float ov = __shfl_down(bv, off);
      const int   oi = __shfl_down(bi, off);
      if (ov < bv || (ov == bv && oi < bi)) { bv = ov; bi = oi; }
    }
    if (lane == 0) { rv[wv] = bv; ri[wv] = bi; }
    __syncthreads();
    if (tid == 0) {
      float fv = rv[0]; int fi = ri[0];
      #pragma unroll
      for (int q = 1; q < 4; ++q)
        if (rv[q] < fv || (rv[q] == fv && ri[q] < fi)) { fv = rv[q]; fi = ri[q]; }
      idxf[row] = fi;
    }
  }
}

__global__ void vq_scatter(const float* __restrict__ z,
                           const float* __restrict__ emb,
                           const int* __restrict__ idx,
                           float* __restrict__ out,
                           float* __restrict__ lossws) {
  __shared__ float part[4];
  const int row = blockIdx.x;
  const int t = threadIdx.x;
  const int code = idx[row];
  const float zv = z[(size_t)row * DIM + t];
  const float ev = emb[(size_t)code * DIM + t];
  const float d = ev - zv;
  out[OUT_ZQ + (size_t)row * DIM + t] = zv + d;
  atomicAdd(out + OUT_SUM + (size_t)code * DIM + t, 0.01f * zv);
  float sq = d * d;
  #pragma unroll
  for (int off = 32; off; off >>= 1) sq += __shfl_down(sq, off);
  const int lane = t & 63, wv = t >> 6;
  if (lane == 0) part[wv] = sq;
  __syncthreads();
  if (t == 0) {
    atomicAdd(lossws, part[0] + part[1] + part[2] + part[3]);
    atomicAdd(out + OUT_CS + code, 0.01f);
    out[OUT_IDX + row] = (float)code;
  }
}

__global__ void vq_finalize(float* __restrict__ out, const float* __restrict__ lossws) {
  const int i = blockIdx.x * blockDim.x + threadIdx.x;
  const int k = i >> 8;
  const float cs = out[OUT_CS + k];
  out[OUT_NEMB + i] = out[OUT_SUM + i] / (cs + 1e-5f);
  if (i == 0) out[OUT_LOSS] = 0.25f * (lossws[0] * (1.f / 8388608.f));
}

extern "C" void kernel_launch(void* const* d_in, const int* in_sizes, int n_in,
                              void* d_out, int out_size, void* d_ws, size_t ws_size,
                              hipStream_t stream) {
  const float* z      = (const float*)d_in[0];
  const float* emb    = (const float*)d_in[1];
  const float* emacs  = (const float*)d_in[2];
  const float* emasum = (const float*)d_in[3];
  float* out = (float*)d_out;
  float* ws  = (float*)d_ws;

  float* esq    = ws;                       // [0, 8192)
  int*   idxf   = (int*)(ws + 8192);        // 32768
  int*   flag   = (int*)(ws + 40960);       // 4096
  int*   cnt    = (int*)(ws + 45056);       // 1
  float* lossws = ws + 45057;               // 1
  short* esp    = (short*)(ws + 46080);     // 8192*768 bf16, 16B-aligned

  vq_esq_np<<<KC / 16, 256, 0, stream>>>(emb, esq);
  vq_esplit<<<(KC * 32) / 256, 256, 0, stream>>>(emb, esp);
  vq_init<<<(KC * DIM) / 256, 256, 0, stream>>>(emasum, emacs, out, lossws, cnt);

  vq_mfma<<<N_TOK / 128, 256, 0, stream>>>(z, esp, esq, idxf, flag, cnt);
  vq_rescan<<<64, 256, 0, stream>>>(z, emb, esq, flag, cnt, idxf);

  vq_scatter<<<N_TOK, 256, 0, stream>>>(z, emb, idxf, out, lossws);
  vq_finalize<<<(KC * DIM) / 256, 256, 0, stream>>>(out, lossws);
}

// Round 5
// 1061.945 us; speedup vs baseline: 8.8015x; 1.0967x over previous
//
#include <hip/hip_runtime.h>
#include <hip/hip_bf16.h>
#include <math.h>

#define N_TOK   32768
#define DIM     256
#define KC      8192

// output layout (flat f32, reference tuple order)
#define OUT_ZQ    0
#define OUT_IDX   8388608          // N_TOK*DIM
#define OUT_LOSS  8421376          // +N_TOK
#define OUT_NEMB  8421377          // +1   (NOTE: odd -> scalar stores only)
#define OUT_CS    10518529         // +KC*DIM
#define OUT_SUM   10526721         // +KC  (odd -> scalar stores only)

#define MARGIN  2.5e-4f
#define FLAGCAP 4096

typedef __attribute__((ext_vector_type(8))) __bf16 bf16x8;
typedef __attribute__((ext_vector_type(4))) float f32x4;

__device__ __forceinline__ void gload16(const void* g, void* l) {
  __builtin_amdgcn_global_load_lds((const __attribute__((address_space(1))) void*)g,
                                   (__attribute__((address_space(3))) void*)l, 16, 0, 0);
}

// ---- numpy pairwise sum-of-squares emulation (validated R3) ----
__device__ __forceinline__ float np_sumsq256(const float* __restrict__ p, int lane) {
  const int l = lane & 15;
  const int h = l >> 3;
  const int j = l & 7;
  const float* a = p + h * 128 + j;
  float x = a[0];
  float r = __fmul_rn(x, x);
  #pragma unroll
  for (int i = 1; i < 16; ++i) {
    x = a[8 * i];
    r = __fadd_rn(r, __fmul_rn(x, x));
  }
  r = __fadd_rn(r, __shfl_down(r, 1));
  r = __fadd_rn(r, __shfl_down(r, 2));
  r = __fadd_rn(r, __shfl_down(r, 4));
  float hi = __shfl(r, (lane & 48) | 8);
  return __fadd_rn(r, hi);
}

__global__ void vq_esq_np(const float* __restrict__ emb, float* __restrict__ esq) {
  const int tid = threadIdx.x;
  const int code = blockIdx.x * 16 + (tid >> 4);
  const float s = np_sumsq256(emb + (size_t)code * DIM, tid & 63);
  if ((tid & 15) == 0) esq[code] = s;
}

// build e_split[8192][768] bf16 = [e_hi | e_hi | e_lo]
__global__ void vq_esplit(const float* __restrict__ emb, short* __restrict__ esp) {
  const int gidx = blockIdx.x * blockDim.x + threadIdx.x;   // [0, 262144)
  const int code = gidx >> 5;
  const int seg  = gidx & 31;
  const float* p = emb + (size_t)code * DIM + seg * 8;
  const float4 v0 = *(const float4*)p;
  const float4 v1 = *(const float4*)(p + 4);
  const float xf[8] = {v0.x, v0.y, v0.z, v0.w, v1.x, v1.y, v1.z, v1.w};
  bf16x8 hi, lo;
  #pragma unroll
  for (int e = 0; e < 8; ++e) {
    __bf16 hb = (__bf16)xf[e];
    hi[e] = hb;
    lo[e] = (__bf16)(xf[e] - (float)hb);
  }
  short* rp = esp + (size_t)code * 768 + seg * 8;
  *(bf16x8*)(rp)       = hi;
  *(bf16x8*)(rp + 256) = hi;
  *(bf16x8*)(rp + 512) = lo;
}

__global__ void vq_init(int* __restrict__ hist, float* __restrict__ lossws,
                        int* __restrict__ cnt) {
  const int i = blockIdx.x * blockDim.x + threadIdx.x;
  hist[i] = 0;
  if (i == 0) { lossws[0] = 0.f; cnt[0] = 0; }
}

// ---- MFMA argmin: 512 blocks (256 row-tiles x 2 code-halves), 256 thr.
// Wave owns 32 rows, A (z hi/lo) in registers; B (e_split) streamed through
// 2x32KB LDS double-buffer organized as 1024B subtiles [16 codes][64B k] so
// every ds_read_b128 instruction reads one contiguous 1024B block. ----
__launch_bounds__(256, 2)
__global__ void vq_mfma(const float* __restrict__ z,
                        const short* __restrict__ esp,
                        const float* __restrict__ esq,
                        float* __restrict__ pb1,
                        int* __restrict__ pi1,
                        float* __restrict__ pb2) {
  __shared__ __align__(16) char lds[65536];
  const int tid  = threadIdx.x;
  const int lane = tid & 63;
  const int w    = tid >> 6;
  const int l15  = lane & 15;
  const int g    = lane >> 4;
  const int rt   = blockIdx.x >> 1;
  const int kh   = blockIdx.x & 1;
  const int row0 = rt * 128 + w * 32;
  const int ct0  = kh * 64, ct1 = ct0 + 64;
  const int gx   = g ^ (l15 & 3);                       // in-subtile rotation
  const int kx16 = ((lane & 3) ^ ((lane >> 2) & 3)) << 4; // stage-side inverse
  const char* espb = (const char*)esp;

  // wave w stages subtiles (S=w, T=q): LDS dest contiguous 1024B, per-lane
  // global source picks code = CT*64 + w*16 + (l>>2), k-byte = q*64 + rot.
#define STAGE(CT, CH, BUFB)                                                     \
  {                                                                             \
    const char* sb_ = espb + (size_t)((CT) * 64 + (w << 4) + (lane >> 2)) * 1536 \
                      + (CH) * 512 + kx16;                                      \
    _Pragma("unroll")                                                           \
    for (int q_ = 0; q_ < 8; ++q_) {                                            \
      gload16(sb_ + (q_ << 6), (void*)(lds + (BUFB) + (((w << 3) + q_) << 10)));\
    }                                                                           \
  }

  STAGE(ct0, 0, 0);

  // A: z rows -> bf16 hi/lo fragments (hi reused for chunk 2)
  bf16x8 Ahi[2][8], Alo[2][8];
  #pragma unroll
  for (int s = 0; s < 2; ++s) {
    const float* zr = z + (size_t)(row0 + s * 16 + l15) * DIM + g * 8;
    #pragma unroll
    for (int c = 0; c < 8; ++c) {
      const float4 v0 = *(const float4*)(zr + c * 32);
      const float4 v1 = *(const float4*)(zr + c * 32 + 4);
      const float xf[8] = {v0.x, v0.y, v0.z, v0.w, v1.x, v1.y, v1.z, v1.w};
      #pragma unroll
      for (int e = 0; e < 8; ++e) {
        __bf16 hb = (__bf16)xf[e];
        Ahi[s][c][e] = hb;
        Alo[s][c][e] = (__bf16)(xf[e] - (float)hb);
      }
    }
  }

  __syncthreads();   // chunk(ct0,0) staged

  float b1[2][4], b2[2][4];
  int   i1[2][4];
  #pragma unroll
  for (int s = 0; s < 2; ++s)
    #pragma unroll
    for (int r = 0; r < 4; ++r) { b1[s][r] = 3.4e38f; b2[s][r] = 3.4e38f; i1[s][r] = 0x7fffffff; }

#define COMP(BUFB, AARR)                                                              \
  {                                                                                   \
    _Pragma("unroll")                                                                 \
    for (int j_ = 0; j_ < 8; ++j_) {                                                  \
      const char* bq_ = lds + (BUFB) + (j_ << 10) + (l15 << 6) + (gx << 4);           \
      const bf16x8 bF0 = *(const bf16x8*)(bq_);                                       \
      const bf16x8 bF1 = *(const bf16x8*)(bq_ + 8192);                                \
      const bf16x8 bF2 = *(const bf16x8*)(bq_ + 16384);                               \
      const bf16x8 bF3 = *(const bf16x8*)(bq_ + 24576);                               \
      acc[0][0] = __builtin_amdgcn_mfma_f32_16x16x32_bf16(AARR[0][j_], bF0, acc[0][0], 0, 0, 0); \
      acc[0][1] = __builtin_amdgcn_mfma_f32_16x16x32_bf16(AARR[0][j_], bF1, acc[0][1], 0, 0, 0); \
      acc[0][2] = __builtin_amdgcn_mfma_f32_16x16x32_bf16(AARR[0][j_], bF2, acc[0][2], 0, 0, 0); \
      acc[0][3] = __builtin_amdgcn_mfma_f32_16x16x32_bf16(AARR[0][j_], bF3, acc[0][3], 0, 0, 0); \
      acc[1][0] = __builtin_amdgcn_mfma_f32_16x16x32_bf16(AARR[1][j_], bF0, acc[1][0], 0, 0, 0); \
      acc[1][1] = __builtin_amdgcn_mfma_f32_16x16x32_bf16(AARR[1][j_], bF1, acc[1][1], 0, 0, 0); \
      acc[1][2] = __builtin_amdgcn_mfma_f32_16x16x32_bf16(AARR[1][j_], bF2, acc[1][2], 0, 0, 0); \
      acc[1][3] = __builtin_amdgcn_mfma_f32_16x16x32_bf16(AARR[1][j_], bF3, acc[1][3], 0, 0, 0); \
    }                                                                                 \
  }

  int bp = 0;
  for (int ct = ct0; ct < ct1; ++ct) {
    float eqv[4];
    #pragma unroll
    for (int sub = 0; sub < 4; ++sub) eqv[sub] = esq[(ct << 6) + sub * 16 + l15];

    f32x4 acc[2][4];
    #pragma unroll
    for (int s = 0; s < 2; ++s)
      #pragma unroll
      for (int sub = 0; sub < 4; ++sub) acc[s][sub] = (f32x4){0.f, 0.f, 0.f, 0.f};

    const int bo  = bp << 15;
    const int bo1 = bo ^ 32768;

    STAGE(ct, 1, bo1);                    // chunk1 (e_hi copy) -> other buf
    COMP(bo, Ahi);                        // chunk0: z_hi . e_hi
    __syncthreads();

    STAGE(ct, 2, bo);                     // chunk2 (e_lo) -> buf0
    COMP(bo1, Alo);                       // chunk1: z_lo . e_hi
    __syncthreads();

    if (ct + 1 < ct1) STAGE(ct + 1, 0, bo1);  // next tile chunk0
    COMP(bo, Ahi);                        // chunk2: z_hi . e_lo
    __syncthreads();

    // epilogue: score = esq - 2*(z.e); track (min, idx) + 2nd-min value
    #pragma unroll
    for (int s = 0; s < 2; ++s) {
      #pragma unroll
      for (int sub = 0; sub < 4; ++sub) {
        const int codeS = (ct << 6) + sub * 16 + l15;
        #pragma unroll
        for (int r = 0; r < 4; ++r) {
          const float sc = fmaf(-2.f, acc[s][sub][r], eqv[sub]);
          const bool lt = sc < b1[s][r];
          b2[s][r] = fminf(b2[s][r], fmaxf(sc, b1[s][r]));
          i1[s][r] = lt ? codeS : i1[s][r];
          b1[s][r] = fminf(b1[s][r], sc);
        }
      }
    }
    bp ^= 1;
  }

  // merge across the 16 lanes sharing each output row; write partials
  #pragma unroll
  for (int s = 0; s < 2; ++s) {
    #pragma unroll
    for (int r = 0; r < 4; ++r) {
      float v1 = b1[s][r], v2 = b2[s][r];
      int   j1 = i1[s][r];
      #pragma unroll
      for (int off = 1; off < 16; off <<= 1) {
        const float o1 = __shfl_xor(v1, off);
        const int   oj = __shfl_xor(j1, off);
        const float o2 = __shfl_xor(v2, off);
        v2 = fminf(fminf(v2, o2), fmaxf(v1, o1));
        const bool tk = (o1 < v1) || (o1 == v1 && oj < j1);
        j1 = tk ? oj : j1;
        v1 = fminf(v1, o1);
      }
      if (l15 == 0) {
        const int rr = kh * N_TOK + row0 + s * 16 + (g << 2) + r;
        pb1[rr] = v1; pi1[rr] = j1; pb2[rr] = v2;
      }
    }
  }
}

// combine the two K-halves' partials; final argmin + near-tie flags
__global__ void vq_merge(const float* __restrict__ pb1, const int* __restrict__ pi1,
                         const float* __restrict__ pb2, int* __restrict__ idxf,
                         int* __restrict__ flag, int* __restrict__ cnt) {
  const int gi = blockIdx.x * blockDim.x + threadIdx.x;
  const float va = pb1[gi],        vb = pb1[N_TOK + gi];
  const int   ia = pi1[gi],        ib = pi1[N_TOK + gi];
  const float v2a = pb2[gi],       v2b = pb2[N_TOK + gi];
  float v1, v2; int i1;
  if (va < vb || (va == vb && ia < ib)) { v1 = va; i1 = ia; v2 = fminf(v2a, vb); }
  else                                  { v1 = vb; i1 = ib; v2 = fminf(v2b, va); }
  idxf[gi] = i1;
  if (v2 - v1 < MARGIN) {
    const int p = atomicAdd(cnt, 1);
    if (p < FLAGCAP) flag[p] = gi;
  }
}

// numpy-exact full rescan for flagged rows (4-way ILP across codes)
__global__ void vq_rescan(const float* __restrict__ z,
                          const float* __restrict__ emb,
                          const float* __restrict__ esq,
                          const int* __restrict__ flag,
                          const int* __restrict__ cnt,
                          int* __restrict__ idxf) {
  __shared__ float zrow[256];
  __shared__ float zsq_sh;
  __shared__ float rv[4];
  __shared__ int   ri[4];
  int n = *cnt; if (n > FLAGCAP) n = FLAGCAP;
  const int tid = threadIdx.x;
  for (int ii = blockIdx.x; ii < n; ii += gridDim.x) {
    const int row = flag[ii];
    __syncthreads();
    zrow[tid] = z[(size_t)row * DIM + tid];
    __syncthreads();
    if (tid < 16) { const float s = np_sumsq256(zrow, tid); if (tid == 0) zsq_sh = s; }
    __syncthreads();
    const float zsq = zsq_sh;
    float bv = 3.4e38f; int bi = 0x7fffffff;
    for (int cc = 0; cc < 32; cc += 4) {
      const float* e0 = emb + (size_t)((cc + 0) * 256 + tid) * DIM;
      const float* e1 = emb + (size_t)((cc + 1) * 256 + tid) * DIM;
      const float* e2 = emb + (size_t)((cc + 2) * 256 + tid) * DIM;
      const float* e3 = emb + (size_t)((cc + 3) * 256 + tid) * DIM;
      float z0 = 0.f, z1 = 0.f, z2 = 0.f, z3 = 0.f;
      #pragma unroll 4
      for (int k = 0; k < DIM; ++k) {
        const float zk = zrow[k];
        z0 = fmaf(zk, e0[k], z0);
        z1 = fmaf(zk, e1[k], z1);
        z2 = fmaf(zk, e2[k], z2);
        z3 = fmaf(zk, e3[k], z3);
      }
      const float zeq[4] = {z0, z1, z2, z3};
      #pragma unroll
      for (int q = 0; q < 4; ++q) {
        const int code = (cc + q) * 256 + tid;
        const float D = __fsub_rn(__fadd_rn(zsq, esq[code]), __fmul_rn(2.f, zeq[q]));
        if (D < bv) { bv = D; bi = code; }
      }
    }
    const int lane = tid & 63, wv = tid >> 6;
    #pragma unroll
    for (int off = 32; off; off >>= 1) {
      const float ov = __shfl_down(bv, off);
      const int   oi = __shfl_down(bi, off);
      if (ov < bv || (ov == bv && oi < bi)) { bv = ov; bi = oi; }
    }
    if (lane == 0) { rv[wv] = bv; ri[wv] = bi; }
    __syncthreads();
    if (tid == 0) {
      float fv = rv[0]; int fi = ri[0];
      #pragma unroll
      for (int q = 1; q < 4; ++q)
        if (rv[q] < fv || (rv[q] == fv && ri[q] < fi)) { fv = rv[q]; fi = ri[q]; }
      idxf[row] = fi;
    }
  }
}

// zq + loss + idx-out + histogram (one wave per row)
__global__ void vq_gather(const float* __restrict__ z, const float* __restrict__ emb,
                          const int* __restrict__ idxf, float* __restrict__ out,
                          float* __restrict__ lossws, int* __restrict__ hist) {
  const int tid = threadIdx.x, lane = tid & 63, w = tid >> 6;
  const int row = blockIdx.x * 4 + w;
  const int code = idxf[row];
  const float4 zv = *(const float4*)(z + (size_t)row * DIM + lane * 4);
  const float4 ev = *(const float4*)(emb + (size_t)code * DIM + lane * 4);
  float4 d, o;
  d.x = ev.x - zv.x; d.y = ev.y - zv.y; d.z = ev.z - zv.z; d.w = ev.w - zv.w;
  o.x = zv.x + d.x;  o.y = zv.y + d.y;  o.z = zv.z + d.z;  o.w = zv.w + d.w;
  *(float4*)(out + OUT_ZQ + (size_t)row * DIM + lane * 4) = o;
  float sq = fmaf(d.x, d.x, fmaf(d.y, d.y, fmaf(d.z, d.z, d.w * d.w)));
  #pragma unroll
  for (int off = 32; off; off >>= 1) sq += __shfl_down(sq, off);
  if (lane == 0) {
    atomicAdd(lossws, sq);
    atomicAdd(hist + code, 1);
    out[OUT_IDX + row] = (float)code;
  }
}

// prefix-scan of histogram; also writes final cluster-size output
__global__ void vq_prefix(const float* __restrict__ ema_cs, int* __restrict__ hist,
                          int* __restrict__ base, int* __restrict__ cursor,
                          float* __restrict__ out) {
  __shared__ int ps[256];
  const int t = threadIdx.x;
  int loc[32]; int s = 0;
  #pragma unroll
  for (int j = 0; j < 32; ++j) { loc[j] = hist[t * 32 + j]; s += loc[j]; }
  ps[t] = s;
  __syncthreads();
  for (int off = 1; off < 256; off <<= 1) {
    const int v = (t >= off) ? ps[t - off] : 0;
    __syncthreads();
    ps[t] += v;
    __syncthreads();
  }
  int run = ps[t] - s;
  #pragma unroll
  for (int j = 0; j < 32; ++j) {
    const int i = t * 32 + j;
    base[i] = run; cursor[i] = run;
    out[OUT_CS + i] = 0.99f * ema_cs[i] + 0.01f * (float)loc[j];
    run += loc[j];
  }
}

__global__ void vq_slot(const int* __restrict__ idxf, int* __restrict__ cursor,
                        int* __restrict__ rowlist) {
  const int gi = blockIdx.x * blockDim.x + threadIdx.x;
  const int code = idxf[gi];
  const int p = atomicAdd(cursor + code, 1);
  rowlist[p] = gi;
}

// per-code segmented sum + EMA + embeddings finalize (+ loss scalar)
__global__ void vq_embsum(const float* __restrict__ z, const float* __restrict__ ema_sum,
                          const int* __restrict__ rowlist, const int* __restrict__ base,
                          const int* __restrict__ hist, const float* __restrict__ lossws,
                          float* __restrict__ out) {
  const int code = blockIdx.x;
  const int lane = threadIdx.x;          // 64 threads = 1 wave
  const int b = base[code], n = hist[code];
  float a0 = 0.f, a1 = 0.f, a2 = 0.f, a3 = 0.f;
  for (int i = 0; i < n; ++i) {
    const float4 v = *(const float4*)(z + (size_t)rowlist[b + i] * DIM + lane * 4);
    a0 += v.x; a1 += v.y; a2 += v.z; a3 += v.w;
  }
  const float4 es = *(const float4*)(ema_sum + (size_t)code * DIM + lane * 4);
  const float s0 = 0.99f * es.x + 0.01f * a0;
  const float s1 = 0.99f * es.y + 0.01f * a1;
  const float s2 = 0.99f * es.z + 0.01f * a2;
  const float s3 = 0.99f * es.w + 0.01f * a3;
  float* sp = out + OUT_SUM + (size_t)code * DIM + lane * 4;   // odd base: scalar stores
  sp[0] = s0; sp[1] = s1; sp[2] = s2; sp[3] = s3;
  const float cs = out[OUT_CS + code] + 1e-5f;
  float* np_ = out + OUT_NEMB + (size_t)code * DIM + lane * 4;
  np_[0] = s0 / cs; np_[1] = s1 / cs; np_[2] = s2 / cs; np_[3] = s3 / cs;
  if (code == 0 && lane == 0)
    out[OUT_LOSS] = 0.25f * (lossws[0] * (1.f / 8388608.f));
}

extern "C" void kernel_launch(void* const* d_in, const int* in_sizes, int n_in,
                              void* d_out, int out_size, void* d_ws, size_t ws_size,
                              hipStream_t stream) {
  const float* z      = (const float*)d_in[0];
  const float* emb    = (const float*)d_in[1];
  const float* emacs  = (const float*)d_in[2];
  const float* emasum = (const float*)d_in[3];
  float* out = (float*)d_out;
  float* ws  = (float*)d_ws;

  // ws layout (f32 words)
  float* esq     = ws;                       // 8192
  int*   idxf    = (int*)(ws + 8192);        // 32768
  int*   flag    = (int*)(ws + 40960);       // 4096
  int*   cnt     = (int*)(ws + 45056);       // 1
  float* lossws  = ws + 45057;               // 1
  int*   hist    = (int*)(ws + 46080);       // 8192
  int*   base    = (int*)(ws + 54272);       // 8192
  int*   cursor  = (int*)(ws + 62464);       // 8192
  int*   rowlist = (int*)(ws + 70656);       // 32768
  float* pb1     = ws + 103424;              // 2*32768
  int*   pi1     = (int*)(ws + 168960);      // 2*32768
  float* pb2     = ws + 234496;              // 2*32768
  short* esp     = (short*)(ws + 300032);    // 8192*768 bf16 (16B-aligned)

  vq_esq_np<<<KC / 16, 256, 0, stream>>>(emb, esq);
  vq_esplit<<<(KC * 32) / 256, 256, 0, stream>>>(emb, esp);
  vq_init<<<KC / 256, 256, 0, stream>>>(hist, lossws, cnt);

  vq_mfma<<<512, 256, 0, stream>>>(z, esp, esq, pb1, pi1, pb2);
  vq_merge<<<N_TOK / 256, 256, 0, stream>>>(pb1, pi1, pb2, idxf, flag, cnt);
  vq_rescan<<<256, 256, 0, stream>>>(z, emb, esq, flag, cnt, idxf);

  vq_gather<<<N_TOK / 4, 256, 0, stream>>>(z, emb, idxf, out, lossws, hist);
  vq_prefix<<<1, 256, 0, stream>>>(emacs, hist, base, cursor, out);
  vq_slot<<<N_TOK / 256, 256, 0, stream>>>(idxf, cursor, rowlist);
  vq_embsum<<<KC, 64, 0, stream>>>(z, emasum, rowlist, base, hist, lossws, out);
}

// Round 6
// 659.343 us; speedup vs baseline: 14.1758x; 1.6106x over previous
//
#include <hip/hip_runtime.h>
#include <hip/hip_bf16.h>
#include <math.h>

#define N_TOK   32768
#define DIM     256
#define KC      8192

// output layout (flat f32, reference tuple order)
#define OUT_ZQ    0
#define OUT_IDX   8388608          // N_TOK*DIM
#define OUT_LOSS  8421376          // +N_TOK
#define OUT_NEMB  8421377          // +1   (NOTE: odd -> scalar stores only)
#define OUT_CS    10518529         // +KC*DIM
#define OUT_SUM   10526721         // +KC  (odd -> scalar stores only)

#define MARGIN  2.5e-4f
#define FLAGCAP 4096

typedef __attribute__((ext_vector_type(8))) __bf16 bf16x8;
typedef __attribute__((ext_vector_type(4))) float f32x4;

__device__ __forceinline__ void gload16(const void* g, void* l) {
  __builtin_amdgcn_global_load_lds((const __attribute__((address_space(1))) void*)g,
                                   (__attribute__((address_space(3))) void*)l, 16, 0, 0);
}

// ---- numpy pairwise sum-of-squares emulation (validated R3) ----
__device__ __forceinline__ float np_sumsq256(const float* __restrict__ p, int lane) {
  const int l = lane & 15;
  const int h = l >> 3;
  const int j = l & 7;
  const float* a = p + h * 128 + j;
  float x = a[0];
  float r = __fmul_rn(x, x);
  #pragma unroll
  for (int i = 1; i < 16; ++i) {
    x = a[8 * i];
    r = __fadd_rn(r, __fmul_rn(x, x));
  }
  r = __fadd_rn(r, __shfl_down(r, 1));
  r = __fadd_rn(r, __shfl_down(r, 2));
  r = __fadd_rn(r, __shfl_down(r, 4));
  float hi = __shfl(r, (lane & 48) | 8);
  return __fadd_rn(r, hi);
}

__global__ void vq_esq_np(const float* __restrict__ emb, float* __restrict__ esq) {
  const int tid = threadIdx.x;
  const int code = blockIdx.x * 16 + (tid >> 4);
  const float s = np_sumsq256(emb + (size_t)code * DIM, tid & 63);
  if ((tid & 15) == 0) esq[code] = s;
}

// build e_split[8192][768] bf16 = [e_hi | e_hi | e_lo]
__global__ void vq_esplit(const float* __restrict__ emb, short* __restrict__ esp) {
  const int gidx = blockIdx.x * blockDim.x + threadIdx.x;   // [0, 262144)
  const int code = gidx >> 5;
  const int seg  = gidx & 31;
  const float* p = emb + (size_t)code * DIM + seg * 8;
  const float4 v0 = *(const float4*)p;
  const float4 v1 = *(const float4*)(p + 4);
  const float xf[8] = {v0.x, v0.y, v0.z, v0.w, v1.x, v1.y, v1.z, v1.w};
  bf16x8 hi, lo;
  #pragma unroll
  for (int e = 0; e < 8; ++e) {
    __bf16 hb = (__bf16)xf[e];
    hi[e] = hb;
    lo[e] = (__bf16)(xf[e] - (float)hb);
  }
  short* rp = esp + (size_t)code * 768 + seg * 8;
  *(bf16x8*)(rp)       = hi;
  *(bf16x8*)(rp + 256) = hi;
  *(bf16x8*)(rp + 512) = lo;
}

__global__ void vq_init(int* __restrict__ hist, int* __restrict__ cnt) {
  const int i = blockIdx.x * blockDim.x + threadIdx.x;
  hist[i] = 0;
  if (i == 0) cnt[0] = 0;
}

// ---- MFMA argmin: 512 blocks (256 row-tiles x 2 code-halves), 256 thr.
// Wave owns 32 rows, A (z hi/lo) in registers; B (e_split) streamed through
// 2x32KB LDS double-buffer organized as 1024B subtiles [16 codes][64B k] so
// every ds_read_b128 instruction reads one contiguous 1024B block. ----
__launch_bounds__(256, 2)
__global__ void vq_mfma(const float* __restrict__ z,
                        const short* __restrict__ esp,
                        const float* __restrict__ esq,
                        float* __restrict__ pb1,
                        int* __restrict__ pi1,
                        float* __restrict__ pb2) {
  __shared__ __align__(16) char lds[65536];
  const int tid  = threadIdx.x;
  const int lane = tid & 63;
  const int w    = tid >> 6;
  const int l15  = lane & 15;
  const int g    = lane >> 4;
  const int rt   = blockIdx.x >> 1;
  const int kh   = blockIdx.x & 1;
  const int row0 = rt * 128 + w * 32;
  const int ct0  = kh * 64, ct1 = ct0 + 64;
  const int gx   = g ^ (l15 & 3);                       // in-subtile rotation
  const int kx16 = ((lane & 3) ^ ((lane >> 2) & 3)) << 4; // stage-side inverse
  const char* espb = (const char*)esp;

  // wave w stages subtiles (S=w, T=q): LDS dest contiguous 1024B, per-lane
  // global source picks code = CT*64 + w*16 + (l>>2), k-byte = q*64 + rot.
#define STAGE(CT, CH, BUFB)                                                     \
  {                                                                             \
    const char* sb_ = espb + (size_t)((CT) * 64 + (w << 4) + (lane >> 2)) * 1536 \
                      + (CH) * 512 + kx16;                                      \
    _Pragma("unroll")                                                           \
    for (int q_ = 0; q_ < 8; ++q_) {                                            \
      gload16(sb_ + (q_ << 6), (void*)(lds + (BUFB) + (((w << 3) + q_) << 10)));\
    }                                                                           \
  }

  STAGE(ct0, 0, 0);

  // A: z rows -> bf16 hi/lo fragments (hi reused for chunk 2)
  bf16x8 Ahi[2][8], Alo[2][8];
  #pragma unroll
  for (int s = 0; s < 2; ++s) {
    const float* zr = z + (size_t)(row0 + s * 16 + l15) * DIM + g * 8;
    #pragma unroll
    for (int c = 0; c < 8; ++c) {
      const float4 v0 = *(const float4*)(zr + c * 32);
      const float4 v1 = *(const float4*)(zr + c * 32 + 4);
      const float xf[8] = {v0.x, v0.y, v0.z, v0.w, v1.x, v1.y, v1.z, v1.w};
      #pragma unroll
      for (int e = 0; e < 8; ++e) {
        __bf16 hb = (__bf16)xf[e];
        Ahi[s][c][e] = hb;
        Alo[s][c][e] = (__bf16)(xf[e] - (float)hb);
      }
    }
  }

  __syncthreads();   // chunk(ct0,0) staged

  float b1[2][4], b2[2][4];
  int   i1[2][4];
  #pragma unroll
  for (int s = 0; s < 2; ++s)
    #pragma unroll
    for (int r = 0; r < 4; ++r) { b1[s][r] = 3.4e38f; b2[s][r] = 3.4e38f; i1[s][r] = 0x7fffffff; }

#define COMP(BUFB, AARR)                                                              \
  {                                                                                   \
    _Pragma("unroll")                                                                 \
    for (int j_ = 0; j_ < 8; ++j_) {                                                  \
      const char* bq_ = lds + (BUFB) + (j_ << 10) + (l15 << 6) + (gx << 4);           \
      const bf16x8 bF0 = *(const bf16x8*)(bq_);                                       \
      const bf16x8 bF1 = *(const bf16x8*)(bq_ + 8192);                                \
      const bf16x8 bF2 = *(const bf16x8*)(bq_ + 16384);                               \
      const bf16x8 bF3 = *(const bf16x8*)(bq_ + 24576);                               \
      acc[0][0] = __builtin_amdgcn_mfma_f32_16x16x32_bf16(AARR[0][j_], bF0, acc[0][0], 0, 0, 0); \
      acc[0][1] = __builtin_amdgcn_mfma_f32_16x16x32_bf16(AARR[0][j_], bF1, acc[0][1], 0, 0, 0); \
      acc[0][2] = __builtin_amdgcn_mfma_f32_16x16x32_bf16(AARR[0][j_], bF2, acc[0][2], 0, 0, 0); \
      acc[0][3] = __builtin_amdgcn_mfma_f32_16x16x32_bf16(AARR[0][j_], bF3, acc[0][3], 0, 0, 0); \
      acc[1][0] = __builtin_amdgcn_mfma_f32_16x16x32_bf16(AARR[1][j_], bF0, acc[1][0], 0, 0, 0); \
      acc[1][1] = __builtin_amdgcn_mfma_f32_16x16x32_bf16(AARR[1][j_], bF1, acc[1][1], 0, 0, 0); \
      acc[1][2] = __builtin_amdgcn_mfma_f32_16x16x32_bf16(AARR[1][j_], bF2, acc[1][2], 0, 0, 0); \
      acc[1][3] = __builtin_amdgcn_mfma_f32_16x16x32_bf16(AARR[1][j_], bF3, acc[1][3], 0, 0, 0); \
    }                                                                                 \
  }

  int bp = 0;
  for (int ct = ct0; ct < ct1; ++ct) {
    float eqv[4];
    #pragma unroll
    for (int sub = 0; sub < 4; ++sub) eqv[sub] = esq[(ct << 6) + sub * 16 + l15];

    f32x4 acc[2][4];
    #pragma unroll
    for (int s = 0; s < 2; ++s)
      #pragma unroll
      for (int sub = 0; sub < 4; ++sub) acc[s][sub] = (f32x4){0.f, 0.f, 0.f, 0.f};

    const int bo  = bp << 15;
    const int bo1 = bo ^ 32768;

    STAGE(ct, 1, bo1);                    // chunk1 (e_hi copy) -> other buf
    COMP(bo, Ahi);                        // chunk0: z_hi . e_hi
    __syncthreads();

    STAGE(ct, 2, bo);                     // chunk2 (e_lo) -> buf0
    COMP(bo1, Alo);                       // chunk1: z_lo . e_hi
    __syncthreads();

    if (ct + 1 < ct1) STAGE(ct + 1, 0, bo1);  // next tile chunk0
    COMP(bo, Ahi);                        // chunk2: z_hi . e_lo
    __syncthreads();

    // epilogue: score = esq - 2*(z.e); track (min, idx) + 2nd-min value
    #pragma unroll
    for (int s = 0; s < 2; ++s) {
      #pragma unroll
      for (int sub = 0; sub < 4; ++sub) {
        const int codeS = (ct << 6) + sub * 16 + l15;
        #pragma unroll
        for (int r = 0; r < 4; ++r) {
          const float sc = fmaf(-2.f, acc[s][sub][r], eqv[sub]);
          const bool lt = sc < b1[s][r];
          b2[s][r] = fminf(b2[s][r], fmaxf(sc, b1[s][r]));
          i1[s][r] = lt ? codeS : i1[s][r];
          b1[s][r] = fminf(b1[s][r], sc);
        }
      }
    }
    bp ^= 1;
  }

  // merge across the 16 lanes sharing each output row; write partials
  #pragma unroll
  for (int s = 0; s < 2; ++s) {
    #pragma unroll
    for (int r = 0; r < 4; ++r) {
      float v1 = b1[s][r], v2 = b2[s][r];
      int   j1 = i1[s][r];
      #pragma unroll
      for (int off = 1; off < 16; off <<= 1) {
        const float o1 = __shfl_xor(v1, off);
        const int   oj = __shfl_xor(j1, off);
        const float o2 = __shfl_xor(v2, off);
        v2 = fminf(fminf(v2, o2), fmaxf(v1, o1));
        const bool tk = (o1 < v1) || (o1 == v1 && oj < j1);
        j1 = tk ? oj : j1;
        v1 = fminf(v1, o1);
      }
      if (l15 == 0) {
        const int rr = kh * N_TOK + row0 + s * 16 + (g << 2) + r;
        pb1[rr] = v1; pi1[rr] = j1; pb2[rr] = v2;
      }
    }
  }
}

// combine the two K-halves' partials; final argmin + near-tie flags
__global__ void vq_merge(const float* __restrict__ pb1, const int* __restrict__ pi1,
                         const float* __restrict__ pb2, int* __restrict__ idxf,
                         int* __restrict__ flag, int* __restrict__ cnt) {
  const int gi = blockIdx.x * blockDim.x + threadIdx.x;
  const float va = pb1[gi],        vb = pb1[N_TOK + gi];
  const int   ia = pi1[gi],        ib = pi1[N_TOK + gi];
  const float v2a = pb2[gi],       v2b = pb2[N_TOK + gi];
  float v1, v2; int i1;
  if (va < vb || (va == vb && ia < ib)) { v1 = va; i1 = ia; v2 = fminf(v2a, vb); }
  else                                  { v1 = vb; i1 = ib; v2 = fminf(v2b, va); }
  idxf[gi] = i1;
  if (v2 - v1 < MARGIN) {
    const int p = atomicAdd(cnt, 1);
    if (p < FLAGCAP) flag[p] = gi;
  }
}

// numpy-exact full rescan for flagged rows (4-way ILP across codes)
__global__ void vq_rescan(const float* __restrict__ z,
                          const float* __restrict__ emb,
                          const float* __restrict__ esq,
                          const int* __restrict__ flag,
                          const int* __restrict__ cnt,
                          int* __restrict__ idxf) {
  __shared__ float zrow[256];
  __shared__ float zsq_sh;
  __shared__ float rv[4];
  __shared__ int   ri[4];
  int n = *cnt; if (n > FLAGCAP) n = FLAGCAP;
  const int tid = threadIdx.x;
  for (int ii = blockIdx.x; ii < n; ii += gridDim.x) {
    const int row = flag[ii];
    __syncthreads();
    zrow[tid] = z[(size_t)row * DIM + tid];
    __syncthreads();
    if (tid < 16) { const float s = np_sumsq256(zrow, tid); if (tid == 0) zsq_sh = s; }
    __syncthreads();
    const float zsq = zsq_sh;
    float bv = 3.4e38f; int bi = 0x7fffffff;
    for (int cc = 0; cc < 32; cc += 4) {
      const float* e0 = emb + (size_t)((cc + 0) * 256 + tid) * DIM;
      const float* e1 = emb + (size_t)((cc + 1) * 256 + tid) * DIM;
      const float* e2 = emb + (size_t)((cc + 2) * 256 + tid) * DIM;
      const float* e3 = emb + (size_t)((cc + 3) * 256 + tid) * DIM;
      float z0 = 0.f, z1 = 0.f, z2 = 0.f, z3 = 0.f;
      #pragma unroll 4
      for (int k = 0; k < DIM; ++k) {
        const float zk = zrow[k];
        z0 = fmaf(zk, e0[k], z0);
        z1 = fmaf(zk, e1[k], z1);
        z2 = fmaf(zk, e2[k], z2);
        z3 = fmaf(zk, e3[k], z3);
      }
      const float zeq[4] = {z0, z1, z2, z3};
      #pragma unroll
      for (int q = 0; q < 4; ++q) {
        const int code = (cc + q) * 256 + tid;
        const float D = __fsub_rn(__fadd_rn(zsq, esq[code]), __fmul_rn(2.f, zeq[q]));
        if (D < bv) { bv = D; bi = code; }
      }
    }
    const int lane = tid & 63, wv = tid >> 6;
    #pragma unroll
    for (int off = 32; off; off >>= 1) {
      const float ov = __shfl_down(bv, off);
      const int   oi = __shfl_down(bi, off);
      if (ov < bv || (ov == bv && oi < bi)) { bv = ov; bi = oi; }
    }
    if (lane == 0) { rv[wv] = bv; ri[wv] = bi; }
    __syncthreads();
    if (tid == 0) {
      float fv = rv[0]; int fi = ri[0];
      #pragma unroll
      for (int q = 1; q < 4; ++q)
        if (rv[q] < fv || (rv[q] == fv && ri[q] < fi)) { fv = rv[q]; fi = ri[q]; }
      idxf[row] = fi;
    }
  }
}

// zq + loss-partials + idx-out + histogram (one wave per row, 4 rows/block)
// NO single-address atomics: per-block loss partial -> lossp[blockIdx.x]
__global__ void vq_gather(const float* __restrict__ z, const float* __restrict__ emb,
                          const int* __restrict__ idxf, float* __restrict__ out,
                          float* __restrict__ lossp, int* __restrict__ hist) {
  __shared__ float part[4];
  const int tid = threadIdx.x, lane = tid & 63, w = tid >> 6;
  const int row = blockIdx.x * 4 + w;
  const int code = idxf[row];
  const float4 zv = *(const float4*)(z + (size_t)row * DIM + lane * 4);
  const float4 ev = *(const float4*)(emb + (size_t)code * DIM + lane * 4);
  float4 d, o;
  d.x = ev.x - zv.x; d.y = ev.y - zv.y; d.z = ev.z - zv.z; d.w = ev.w - zv.w;
  o.x = zv.x + d.x;  o.y = zv.y + d.y;  o.z = zv.z + d.z;  o.w = zv.w + d.w;
  *(float4*)(out + OUT_ZQ + (size_t)row * DIM + lane * 4) = o;
  float sq = fmaf(d.x, d.x, fmaf(d.y, d.y, fmaf(d.z, d.z, d.w * d.w)));
  #pragma unroll
  for (int off = 32; off; off >>= 1) sq += __shfl_down(sq, off);
  if (lane == 0) {
    part[w] = sq;
    atomicAdd(hist + code, 1);
    out[OUT_IDX + row] = (float)code;
  }
  __syncthreads();
  if (tid == 0) lossp[blockIdx.x] = (part[0] + part[1]) + (part[2] + part[3]);
}

// prefix-scan of histogram + cluster-size output + loss reduction (1 block)
__global__ void vq_prefix(const float* __restrict__ ema_cs, int* __restrict__ hist,
                          int* __restrict__ base, int* __restrict__ cursor,
                          const float* __restrict__ lossp, float* __restrict__ out) {
  __shared__ int ps[256];
  __shared__ float lp[4];
  const int t = threadIdx.x;

  // loss: 8192 partials, 32 per thread (float4 loads), wave+LDS reduce
  float ls = 0.f;
  #pragma unroll
  for (int j = 0; j < 8; ++j) {
    const float4 v = *(const float4*)(lossp + t * 32 + j * 4);
    ls += (v.x + v.y) + (v.z + v.w);
  }
  #pragma unroll
  for (int off = 32; off; off >>= 1) ls += __shfl_down(ls, off);
  if ((t & 63) == 0) lp[t >> 6] = ls;

  int loc[32]; int s = 0;
  #pragma unroll
  for (int j = 0; j < 32; ++j) { loc[j] = hist[t * 32 + j]; s += loc[j]; }
  ps[t] = s;
  __syncthreads();
  if (t == 0)
    out[OUT_LOSS] = 0.25f * (((lp[0] + lp[1]) + (lp[2] + lp[3])) * (1.f / 8388608.f));
  for (int off = 1; off < 256; off <<= 1) {
    const int v = (t >= off) ? ps[t - off] : 0;
    __syncthreads();
    ps[t] += v;
    __syncthreads();
  }
  int run = ps[t] - s;
  #pragma unroll
  for (int j = 0; j < 32; ++j) {
    const int i = t * 32 + j;
    base[i] = run; cursor[i] = run;
    out[OUT_CS + i] = 0.99f * ema_cs[i] + 0.01f * (float)loc[j];
    run += loc[j];
  }
}

__global__ void vq_slot(const int* __restrict__ idxf, int* __restrict__ cursor,
                        int* __restrict__ rowlist) {
  const int gi = blockIdx.x * blockDim.x + threadIdx.x;
  const int code = idxf[gi];
  const int p = atomicAdd(cursor + code, 1);
  rowlist[p] = gi;
}

// per-code segmented sum + EMA + embeddings finalize
__global__ void vq_embsum(const float* __restrict__ z, const float* __restrict__ ema_sum,
                          const int* __restrict__ rowlist, const int* __restrict__ base,
                          const int* __restrict__ hist, float* __restrict__ out) {
  const int code = blockIdx.x;
  const int lane = threadIdx.x;          // 64 threads = 1 wave
  const int b = base[code], n = hist[code];
  float a0 = 0.f, a1 = 0.f, a2 = 0.f, a3 = 0.f;
  for (int i = 0; i < n; ++i) {
    const float4 v = *(const float4*)(z + (size_t)rowlist[b + i] * DIM + lane * 4);
    a0 += v.x; a1 += v.y; a2 += v.z; a3 += v.w;
  }
  const float4 es = *(const float4*)(ema_sum + (size_t)code * DIM + lane * 4);
  const float s0 = 0.99f * es.x + 0.01f * a0;
  const float s1 = 0.99f * es.y + 0.01f * a1;
  const float s2 = 0.99f * es.z + 0.01f * a2;
  const float s3 = 0.99f * es.w + 0.01f * a3;
  float* sp = out + OUT_SUM + (size_t)code * DIM + lane * 4;   // odd base: scalar stores
  sp[0] = s0; sp[1] = s1; sp[2] = s2; sp[3] = s3;
  const float cs = out[OUT_CS + code] + 1e-5f;
  float* np_ = out + OUT_NEMB + (size_t)code * DIM + lane * 4;
  np_[0] = s0 / cs; np_[1] = s1 / cs; np_[2] = s2 / cs; np_[3] = s3 / cs;
}

extern "C" void kernel_launch(void* const* d_in, const int* in_sizes, int n_in,
                              void* d_out, int out_size, void* d_ws, size_t ws_size,
                              hipStream_t stream) {
  const float* z      = (const float*)d_in[0];
  const float* emb    = (const float*)d_in[1];
  const float* emacs  = (const float*)d_in[2];
  const float* emasum = (const float*)d_in[3];
  float* out = (float*)d_out;
  float* ws  = (float*)d_ws;

  // ws layout (f32 words)
  float* esq     = ws;                       // 8192
  int*   idxf    = (int*)(ws + 8192);        // 32768
  int*   flag    = (int*)(ws + 40960);       // 4096
  int*   cnt     = (int*)(ws + 45056);       // 1
  int*   hist    = (int*)(ws + 46080);       // 8192
  int*   base    = (int*)(ws + 54272);       // 8192
  int*   cursor  = (int*)(ws + 62464);       // 8192
  int*   rowlist = (int*)(ws + 70656);       // 32768
  float* pb1     = ws + 103424;              // 2*32768 (aliased as lossp later)
  int*   pi1     = (int*)(ws + 168960);      // 2*32768
  float* pb2     = ws + 234496;              // 2*32768
  short* esp     = (short*)(ws + 300032);    // 8192*768 bf16 (16B-aligned)
  float* lossp   = pb1;                      // 8192 partials; pb1 is dead by then

  vq_esq_np<<<KC / 16, 256, 0, stream>>>(emb, esq);
  vq_esplit<<<(KC * 32) / 256, 256, 0, stream>>>(emb, esp);
  vq_init<<<KC / 256, 256, 0, stream>>>(hist, cnt);

  vq_mfma<<<512, 256, 0, stream>>>(z, esp, esq, pb1, pi1, pb2);
  vq_merge<<<N_TOK / 256, 256, 0, stream>>>(pb1, pi1, pb2, idxf, flag, cnt);
  vq_rescan<<<256, 256, 0, stream>>>(z, emb, esq, flag, cnt, idxf);

  vq_gather<<<N_TOK / 4, 256, 0, stream>>>(z, emb, idxf, out, lossp, hist);
  vq_prefix<<<1, 256, 0, stream>>>(emacs, hist, base, cursor, lossp, out);
  vq_slot<<<N_TOK / 256, 256, 0, stream>>>(idxf, cursor, rowlist);
  vq_embsum<<<KC, 64, 0, stream>>>(z, emasum, rowlist, base, hist, out);
}